// Round 1
// baseline (2157.170 us; speedup 1.0000x reference)
//
#include <hip/hip_runtime.h>
#include <math.h>

#define L_  50
#define T_  100
#define D_  128
#define NEG_INF_ -9000000000000000.0f

__device__ __forceinline__ float wred_sum(float v) {
#pragma unroll
    for (int o = 32; o > 0; o >>= 1) v += __shfl_xor(v, o, 64);
    return v;
}
__device__ __forceinline__ float wred_max(float v) {
#pragma unroll
    for (int o = 32; o > 0; o >>= 1) v = fmaxf(v, __shfl_xor(v, o, 64));
    return v;
}
__device__ __forceinline__ float rdlane(float v, int l) {
    return __uint_as_float(__builtin_amdgcn_readlane(__float_as_uint(v), l));
}

// h[l][g] = op( sum_d x[l][d] * W[d][g] (+ bias[g]) )
// 256 threads: lq = tid&15 (row group, rows lq, lq+16, lq+32 [, lq+48 if lq<2]),
// g0 = (tid>>4)*8 (8 consecutive output cols). W staged in 16-row chunks in LDS.
template <int MODE>  // 0: raw store, 1: tanh(acc + bias)
__device__ __forceinline__ void gemm50(const float* __restrict__ W,
                                       const float* __restrict__ bias,
                                       float (&xin)[50][132], float (&hout)[50][132],
                                       float (&wst)[16][128], int tid) {
    const int lq = tid & 15;
    const int g0 = (tid >> 4) << 3;
    const int nl = (lq < 2) ? 4 : 3;
    float acc[4][8];
#pragma unroll
    for (int i = 0; i < 4; ++i)
#pragma unroll
        for (int j = 0; j < 8; ++j) acc[i][j] = 0.f;

    for (int d0 = 0; d0 < 128; d0 += 16) {
#pragma unroll
        for (int k = 0; k < 2; ++k) {
            const int idx = tid + (k << 8);
            const int row = idx >> 5, col = (idx & 31) << 2;
            *(float4*)&wst[row][col] = *(const float4*)&W[(d0 + row) * 128 + col];
        }
        __syncthreads();
#pragma unroll
        for (int q = 0; q < 4; ++q) {
            float4 xq[4];
#pragma unroll
            for (int il = 0; il < 4; ++il)
                if (il < nl)
                    xq[il] = *(const float4*)&xin[lq + (il << 4)][d0 + (q << 2)];
#pragma unroll
            for (int dq = 0; dq < 4; ++dq) {
                const float4 wa = *(const float4*)&wst[(q << 2) + dq][g0];
                const float4 wb = *(const float4*)&wst[(q << 2) + dq][g0 + 4];
#pragma unroll
                for (int il = 0; il < 4; ++il)
                    if (il < nl) {
                        const float xs = (dq == 0) ? xq[il].x
                                       : (dq == 1) ? xq[il].y
                                       : (dq == 2) ? xq[il].z
                                                   : xq[il].w;
                        acc[il][0] = fmaf(xs, wa.x, acc[il][0]);
                        acc[il][1] = fmaf(xs, wa.y, acc[il][1]);
                        acc[il][2] = fmaf(xs, wa.z, acc[il][2]);
                        acc[il][3] = fmaf(xs, wa.w, acc[il][3]);
                        acc[il][4] = fmaf(xs, wb.x, acc[il][4]);
                        acc[il][5] = fmaf(xs, wb.y, acc[il][5]);
                        acc[il][6] = fmaf(xs, wb.z, acc[il][6]);
                        acc[il][7] = fmaf(xs, wb.w, acc[il][7]);
                    }
            }
        }
        __syncthreads();
    }

    float4 ba, bb;
    if (MODE == 1) {
        ba = *(const float4*)&bias[g0];
        bb = *(const float4*)&bias[g0 + 4];
    }
#pragma unroll
    for (int il = 0; il < 4; ++il)
        if (il < nl) {
            const int l = lq + (il << 4);
            if (MODE == 1) {
                hout[l][g0 + 0] = tanhf(acc[il][0] + ba.x);
                hout[l][g0 + 1] = tanhf(acc[il][1] + ba.y);
                hout[l][g0 + 2] = tanhf(acc[il][2] + ba.z);
                hout[l][g0 + 3] = tanhf(acc[il][3] + ba.w);
                hout[l][g0 + 4] = tanhf(acc[il][4] + bb.x);
                hout[l][g0 + 5] = tanhf(acc[il][5] + bb.y);
                hout[l][g0 + 6] = tanhf(acc[il][6] + bb.z);
                hout[l][g0 + 7] = tanhf(acc[il][7] + bb.w);
            } else {
                *(float4*)&hout[l][g0] =
                    make_float4(acc[il][0], acc[il][1], acc[il][2], acc[il][3]);
                *(float4*)&hout[l][g0 + 4] =
                    make_float4(acc[il][4], acc[il][5], acc[il][6], acc[il][7]);
            }
        }
}

extern "C" __global__ void __launch_bounds__(256) magnn_fused(
    const int* __restrict__ iseq, const int* __restrict__ uids,
    const int* __restrict__ itp, const int* __restrict__ A,
    const float* __restrict__ item_emb, const float* __restrict__ user_emb,
    const float* __restrict__ W2t, const float* __restrict__ b2t,
    const float* __restrict__ W_att, const float* __restrict__ a_att,
    const float* __restrict__ W_out, const float* __restrict__ a_out,
    const float* __restrict__ att1_W, const float* __restrict__ att1_b,
    const float* __restrict__ att2_W, const float* __restrict__ att2_b,
    const float* __restrict__ user_com, float* __restrict__ out) {
    __shared__ __align__(16) float x[50][132];   // 26400 B (132 = pad to break stride-128 conflicts)
    __shared__ __align__(16) float h[50][132];   // 26400 B
    __shared__ __align__(16) float wst[16][128]; //  8192 B
    __shared__ float f1s[64], f2s[64];
    __shared__ __align__(16) float attn_sm[50][4];
    __shared__ __align__(16) float cat[256];
    __shared__ float svlo[128], svhi[128];
    __shared__ float fpart[128];
    float* vvec = &cat[0];  // cat dead after fusion accumulation

    const int tid = threadIdx.x;
    const int b = blockIdx.x;
    const int w = tid >> 6, lane = tid & 63;

    // ---- gather item embeddings into x ----
    {
        const int* isq = iseq + b * L_;
        for (int i = tid; i < L_ * 32; i += 256) {
            const int l = i >> 5, c4 = (i & 31) << 2;
            const int it = isq[l];
            *(float4*)&x[l][c4] = *(const float4*)&item_emb[(size_t)it * D_ + c4];
        }
    }
    __syncthreads();

    // ---- s[d] = sum_l item_embs[l][d] (for rel_score), split in two halves ----
    if (tid < 128) {
        float s = 0.f;
        for (int l = 0; l < 25; ++l) s += x[l][tid];
        svlo[tid] = s;
    } else {
        const int d = tid - 128;
        float s = 0.f;
        for (int l = 25; l < 50; ++l) s += x[l][d];
        svhi[d] = s;
    }

    // ---- 2 GAT layers: x = elu(softmax_adj(tanh(f1_i+f2_j)) @ (x@W)) ----
#pragma unroll 1
    for (int layer = 0; layer < 2; ++layer) {
        const float* Wl = layer ? W_out : W_att;
        const float* al = layer ? a_out : a_att;
        __syncthreads();
        gemm50<0>(Wl, nullptr, x, h, wst, tid);
        __syncthreads();
        // f1[l] = h[l,:]·a[:128], f2[l] = h[l,:]·a[128:]
        {
            const float a1l = al[lane], a1h = al[lane + 64];
            const float a2l = al[128 + lane], a2h = al[192 + lane];
            for (int l = w; l < L_; l += 4) {
                const float h0 = h[l][lane], h1 = h[l][lane + 64];
                const float r1 = wred_sum(fmaf(h0, a1l, h1 * a1h));
                const float r2 = wred_sum(fmaf(h0, a2l, h1 * a2h));
                if (lane == 0) { f1s[l] = r1; f2s[l] = r2; }
            }
        }
        __syncthreads();
        // masked softmax rows + h' = att @ h, 4 rows per wave-group
        {
            const int* Ab = A + (size_t)b * (L_ * L_);
            const float f2v = (lane < L_) ? f2s[lane] : 0.f;
            for (int k0 = 0; k0 < 13; k0 += 4) {
                float attv[4];
                int lr[4];
                bool vr[4];
#pragma unroll
                for (int r = 0; r < 4; ++r) {
                    const int k = k0 + r;
                    const int l = w + 4 * k;
                    lr[r] = l;
                    vr[r] = (k < 13) && (l < L_);
                    attv[r] = 0.f;
                    if (vr[r]) {
                        const float f1l = f1s[l];
                        const int adj = (lane < L_) ? Ab[l * L_ + lane] : 0;
                        const float e = tanhf(f1l + f2v);
                        const float val =
                            (lane < L_) ? (adj > 0 ? e : NEG_INF_) : -INFINITY;
                        const float m = wred_max(val);
                        const float p = __expf(val - m);
                        const float s = wred_sum(p);
                        attv[r] = p / s;
                    }
                }
                float ac0[4] = {0.f, 0.f, 0.f, 0.f}, ac1[4] = {0.f, 0.f, 0.f, 0.f};
#pragma unroll
                for (int j = 0; j < L_; ++j) {
                    const float h0 = h[j][lane], h1 = h[j][lane + 64];
#pragma unroll
                    for (int r = 0; r < 4; ++r) {
                        const float aj = rdlane(attv[r], j);
                        ac0[r] = fmaf(aj, h0, ac0[r]);
                        ac1[r] = fmaf(aj, h1, ac1[r]);
                    }
                }
#pragma unroll
                for (int r = 0; r < 4; ++r)
                    if (vr[r]) {
                        const float e0 = ac0[r], e1 = ac1[r];
                        x[lr[r]][lane] = e0 > 0.f ? e0 : expm1f(e0);
                        x[lr[r]][lane + 64] = e1 > 0.f ? e1 : expm1f(e1);
                    }
            }
        }
    }
    __syncthreads();

    // ---- m1 = tanh(x @ att1_W + att1_b) -> h ----
    gemm50<1>(att1_W, att1_b, x, h, wst, tid);
    __syncthreads();

    // ---- m2 = m1 @ att2_W + att2_b; attn = softmax over H=4 ----
    {
        const float4 awl = *(const float4*)&att2_W[lane * 4];
        const float4 awh = *(const float4*)&att2_W[(lane + 64) * 4];
        const float bb0 = att2_b[0], bb1 = att2_b[1], bb2 = att2_b[2], bb3 = att2_b[3];
        for (int l = w; l < L_; l += 4) {
            const float q0 = h[l][lane], q1 = h[l][lane + 64];
            float m0 = wred_sum(fmaf(q0, awl.x, q1 * awh.x)) + bb0;
            float m1 = wred_sum(fmaf(q0, awl.y, q1 * awh.y)) + bb1;
            float m2 = wred_sum(fmaf(q0, awl.z, q1 * awh.z)) + bb2;
            float m3 = wred_sum(fmaf(q0, awl.w, q1 * awh.w)) + bb3;
            const float mx = fmaxf(fmaxf(m0, m1), fmaxf(m2, m3));
            const float e0 = __expf(m0 - mx), e1 = __expf(m1 - mx);
            const float e2 = __expf(m2 - mx), e3 = __expf(m3 - mx);
            const float inv = 1.f / (e0 + e1 + e2 + e3);
            if (lane == 0)
                *(float4*)&attn_sm[l][0] =
                    make_float4(e0 * inv, e1 * inv, e2 * inv, e3 * inv);
        }
    }
    __syncthreads();

    // ---- matrix_z / attention_embs -> cat[0:128]; user_emb -> cat[128:256] ----
    if (tid < 128) {
        const int d = tid;
        float z0 = 0.f, z1 = 0.f, z2 = 0.f, z3 = 0.f;
        for (int l = 0; l < L_; ++l) {
            const float xv = x[l][d];
            const float4 at = *(const float4*)&attn_sm[l][0];
            z0 = fmaf(xv, at.x, z0);
            z1 = fmaf(xv, at.y, z1);
            z2 = fmaf(xv, at.z, z2);
            z3 = fmaf(xv, at.w, z3);
        }
        cat[d] = 0.25f * (tanhf(z0) + tanhf(z1) + tanhf(z2) + tanhf(z3));
    } else {
        const int d = tid - 128;
        const int uid = uids[b];
        cat[tid] = user_emb[(size_t)uid * D_ + d];
    }
    __syncthreads();

    // ---- fusion = cat @ user_com; v = fusion + s ----
    {
        const int g = tid & 127, hf = tid >> 7;
        float acc = 0.f;
        const float* ucb = user_com + hf * 128 * 128 + g;
        const float* cc = &cat[hf * 128];
#pragma unroll 4
        for (int k = 0; k < 128; ++k) acc = fmaf(cc[k], ucb[(size_t)k * 128], acc);
        if (hf) fpart[g] = acc;
        __syncthreads();
        if (!hf) vvec[g] = acc + fpart[g] + svlo[g] + svhi[g];
    }
    __syncthreads();

    // ---- out[b,t] = w2[t]·v + b2[t] ----
    {
        const float vl = vvec[lane], vh = vvec[lane + 64];
        const int* itpb = itp + b * T_;
        for (int t = w; t < T_; t += 4) {
            const int item = itpb[t];
            const float* w2r = W2t + (size_t)item * D_;
            float r = fmaf(w2r[lane], vl, w2r[lane + 64] * vh);
            r = wred_sum(r);
            if (lane == 0) out[b * T_ + t] = r + b2t[item];
        }
    }
}

extern "C" void kernel_launch(void* const* d_in, const int* in_sizes, int n_in,
                              void* d_out, int out_size, void* d_ws, size_t ws_size,
                              hipStream_t stream) {
    const int* iseq = (const int*)d_in[0];
    const int* uids = (const int*)d_in[1];
    const int* itp = (const int*)d_in[2];
    const int* A = (const int*)d_in[3];
    const float* item_emb = (const float*)d_in[4];
    const float* user_emb = (const float*)d_in[5];
    const float* W2t = (const float*)d_in[6];
    const float* b2t = (const float*)d_in[7];
    const float* W_att = (const float*)d_in[8];
    const float* a_att = (const float*)d_in[9];
    const float* W_out = (const float*)d_in[10];
    const float* a_out = (const float*)d_in[11];
    const float* att1_W = (const float*)d_in[12];
    const float* att1_b = (const float*)d_in[13];
    const float* att2_W = (const float*)d_in[14];
    const float* att2_b = (const float*)d_in[15];
    const float* user_com = (const float*)d_in[16];
    float* out = (float*)d_out;

    const int B = in_sizes[1];  // user_ids is (B,)
    magnn_fused<<<dim3(B), dim3(256), 0, stream>>>(
        iseq, uids, itp, A, item_emb, user_emb, W2t, b2t, W_att, a_att, W_out,
        a_out, att1_W, att1_b, att2_W, att2_b, user_com, out);
}

// Round 2
// 1408.095 us; speedup vs baseline: 1.5320x; 1.5320x over previous
//
#include <hip/hip_runtime.h>
#include <math.h>

#define L_  50
#define T_  100
#define D_  128
#define NEG_INF_ -9000000000000000.0f

__device__ __forceinline__ float wred_sum(float v) {
#pragma unroll
    for (int o = 32; o > 0; o >>= 1) v += __shfl_xor(v, o, 64);
    return v;
}
__device__ __forceinline__ float wred_max(float v) {
#pragma unroll
    for (int o = 32; o > 0; o >>= 1) v = fmaxf(v, __shfl_xor(v, o, 64));
    return v;
}
__device__ __forceinline__ float rdlane(float v, int l) {
    return __uint_as_float(__builtin_amdgcn_readlane(__float_as_uint(v), l));
}

// h[l][g] = op( sum_d x[l][d] * W[d][g] (+ bias[g]) )
// 256 threads: lq = tid&15 (rows lq, lq+16, lq+32 [, lq+48 if lq<2]),
// g0 = (tid>>4)*8 (8 consecutive output cols). W streamed from global
// (L1/L2-resident, 16 lanes share each address -> coalesces to 1-2 lines).
// NO internal barriers.
template <int MODE>  // 0: raw store, 1: tanh(acc + bias)
__device__ __forceinline__ void gemm50(const float* __restrict__ W,
                                       const float* __restrict__ bias,
                                       const float (&xin)[50][128],
                                       float (&hout)[50][128], int tid) {
    const int lq = tid & 15;
    const int g0 = (tid >> 4) << 3;
    const int nl = (lq < 2) ? 4 : 3;
    float acc[4][8];
#pragma unroll
    for (int i = 0; i < 4; ++i)
#pragma unroll
        for (int j = 0; j < 8; ++j) acc[i][j] = 0.f;

    const float* Wg = W + g0;
#pragma unroll 2
    for (int d0 = 0; d0 < 128; d0 += 4) {
        float4 wv[4][2];
#pragma unroll
        for (int k = 0; k < 4; ++k) {
            const float* wr = Wg + (size_t)(d0 + k) * 128;
            wv[k][0] = *(const float4*)wr;
            wv[k][1] = *(const float4*)(wr + 4);
        }
        float4 xq[4];
#pragma unroll
        for (int il = 0; il < 4; ++il)
            if (il < nl) xq[il] = *(const float4*)&xin[lq + (il << 4)][d0];
#pragma unroll
        for (int k = 0; k < 4; ++k) {
            const float4 wa = wv[k][0], wb = wv[k][1];
#pragma unroll
            for (int il = 0; il < 4; ++il)
                if (il < nl) {
                    const float xs = (k == 0) ? xq[il].x
                                   : (k == 1) ? xq[il].y
                                   : (k == 2) ? xq[il].z
                                              : xq[il].w;
                    acc[il][0] = fmaf(xs, wa.x, acc[il][0]);
                    acc[il][1] = fmaf(xs, wa.y, acc[il][1]);
                    acc[il][2] = fmaf(xs, wa.z, acc[il][2]);
                    acc[il][3] = fmaf(xs, wa.w, acc[il][3]);
                    acc[il][4] = fmaf(xs, wb.x, acc[il][4]);
                    acc[il][5] = fmaf(xs, wb.y, acc[il][5]);
                    acc[il][6] = fmaf(xs, wb.z, acc[il][6]);
                    acc[il][7] = fmaf(xs, wb.w, acc[il][7]);
                }
        }
    }

    float4 ba, bb;
    if (MODE == 1) {
        ba = *(const float4*)&bias[g0];
        bb = *(const float4*)&bias[g0 + 4];
    }
#pragma unroll
    for (int il = 0; il < 4; ++il)
        if (il < nl) {
            const int l = lq + (il << 4);
            if (MODE == 1) {
                hout[l][g0 + 0] = tanhf(acc[il][0] + ba.x);
                hout[l][g0 + 1] = tanhf(acc[il][1] + ba.y);
                hout[l][g0 + 2] = tanhf(acc[il][2] + ba.z);
                hout[l][g0 + 3] = tanhf(acc[il][3] + ba.w);
                hout[l][g0 + 4] = tanhf(acc[il][4] + bb.x);
                hout[l][g0 + 5] = tanhf(acc[il][5] + bb.y);
                hout[l][g0 + 6] = tanhf(acc[il][6] + bb.z);
                hout[l][g0 + 7] = tanhf(acc[il][7] + bb.w);
            } else {
                *(float4*)&hout[l][g0] =
                    make_float4(acc[il][0], acc[il][1], acc[il][2], acc[il][3]);
                *(float4*)&hout[l][g0 + 4] =
                    make_float4(acc[il][4], acc[il][5], acc[il][6], acc[il][7]);
            }
        }
}

extern "C" __global__ void __launch_bounds__(256, 3) magnn_fused(
    const int* __restrict__ iseq, const int* __restrict__ uids,
    const int* __restrict__ itp, const int* __restrict__ A,
    const float* __restrict__ item_emb, const float* __restrict__ user_emb,
    const float* __restrict__ W2t, const float* __restrict__ b2t,
    const float* __restrict__ W_att, const float* __restrict__ a_att,
    const float* __restrict__ W_out, const float* __restrict__ a_out,
    const float* __restrict__ att1_W, const float* __restrict__ att1_b,
    const float* __restrict__ att2_W, const float* __restrict__ att2_b,
    const float* __restrict__ user_com, float* __restrict__ out) {
    // LDS budget: 2*25600 + 2560 = 53760 B -> 3 blocks/CU (<= 54613 B)
    __shared__ __align__(16) float x[50][128];
    __shared__ __align__(16) float h[50][128];
    __shared__ __align__(16) float scratch[640];
    // phase-local aliases (non-overlapping lifetimes):
    float* f1s = scratch;            // [64]  GAT
    float* f2s = scratch + 64;       // [64]  GAT
    float* attn_sm = scratch;        // [200] m2 -> matrix_z   (50 x 4)
    float* cat = scratch + 256;      // [256] matrix_z -> fusion
    float* vvec = scratch;           // [128] fusion -> out (attn dead)
    float* fpart = scratch + 128;    // [128] fusion

    const int tid = threadIdx.x;
    const int b = blockIdx.x;
    const int w = tid >> 6, lane = tid & 63;

    // ---- gather item embeddings into x ----
    {
        const int* isq = iseq + b * L_;
        for (int i = tid; i < L_ * 32; i += 256) {
            const int l = i >> 5, c4 = (i & 31) << 2;
            const int it = isq[l];
            *(float4*)&x[l][c4] = *(const float4*)&item_emb[(size_t)it * D_ + c4];
        }
    }
    __syncthreads();

    // ---- s[d] = sum_l item_embs[l][d], kept in a register of thread d<128 ----
    float sval = 0.f;
    if (tid < 128) {
#pragma unroll 5
        for (int l = 0; l < L_; ++l) sval += x[l][tid];
    }

    // ---- 2 GAT layers: x = elu(softmax_adj(tanh(f1_i+f2_j)) @ (x@W)) ----
#pragma unroll 1
    for (int layer = 0; layer < 2; ++layer) {
        const float* Wl = layer ? W_out : W_att;
        const float* al = layer ? a_out : a_att;
        gemm50<0>(Wl, nullptr, x, h, tid);
        __syncthreads();
        // f1[l] = h[l,:]·a[:128], f2[l] = h[l,:]·a[128:]
        {
            const float a1l = al[lane], a1h = al[lane + 64];
            const float a2l = al[128 + lane], a2h = al[192 + lane];
            for (int l = w; l < L_; l += 4) {
                const float h0 = h[l][lane], h1 = h[l][lane + 64];
                const float r1 = wred_sum(fmaf(h0, a1l, h1 * a1h));
                const float r2 = wred_sum(fmaf(h0, a2l, h1 * a2h));
                if (lane == 0) { f1s[l] = r1; f2s[l] = r2; }
            }
        }
        __syncthreads();
        // masked softmax rows + h' = att @ h, 4 rows per wave
        {
            const int* Ab = A + (size_t)b * (L_ * L_);
            const float f2v = (lane < L_) ? f2s[lane] : 0.f;
            for (int k0 = 0; k0 < 13; k0 += 4) {
                float attv[4];
                int lr[4];
                bool vr[4];
#pragma unroll
                for (int r = 0; r < 4; ++r) {
                    const int k = k0 + r;
                    const int l = w + 4 * k;
                    lr[r] = l;
                    vr[r] = (k < 13) && (l < L_);
                    attv[r] = 0.f;
                    if (vr[r]) {
                        const float f1l = f1s[l];
                        const int adj = (lane < L_) ? Ab[l * L_ + lane] : 0;
                        const float e = tanhf(f1l + f2v);
                        const float val =
                            (lane < L_) ? (adj > 0 ? e : NEG_INF_) : -INFINITY;
                        const float m = wred_max(val);
                        const float p = __expf(val - m);
                        const float s = wred_sum(p);
                        attv[r] = p / s;
                    }
                }
                float ac0[4] = {0.f, 0.f, 0.f, 0.f}, ac1[4] = {0.f, 0.f, 0.f, 0.f};
#pragma unroll
                for (int j = 0; j < L_; ++j) {
                    const float h0 = h[j][lane], h1 = h[j][lane + 64];
#pragma unroll
                    for (int r = 0; r < 4; ++r) {
                        const float aj = rdlane(attv[r], j);
                        ac0[r] = fmaf(aj, h0, ac0[r]);
                        ac1[r] = fmaf(aj, h1, ac1[r]);
                    }
                }
#pragma unroll
                for (int r = 0; r < 4; ++r)
                    if (vr[r]) {
                        const float e0 = ac0[r], e1 = ac1[r];
                        x[lr[r]][lane] = e0 > 0.f ? e0 : expm1f(e0);
                        x[lr[r]][lane + 64] = e1 > 0.f ? e1 : expm1f(e1);
                    }
            }
        }
        __syncthreads();
    }

    // ---- m1 = tanh(x @ att1_W + att1_b) -> h ----
    gemm50<1>(att1_W, att1_b, x, h, tid);
    __syncthreads();

    // ---- m2 = m1 @ att2_W + att2_b; attn = softmax over H=4 ----
    {
        const float4 awl = *(const float4*)&att2_W[lane * 4];
        const float4 awh = *(const float4*)&att2_W[(lane + 64) * 4];
        const float bb0 = att2_b[0], bb1 = att2_b[1], bb2 = att2_b[2], bb3 = att2_b[3];
        for (int l = w; l < L_; l += 4) {
            const float q0 = h[l][lane], q1 = h[l][lane + 64];
            float m0 = wred_sum(fmaf(q0, awl.x, q1 * awh.x)) + bb0;
            float m1 = wred_sum(fmaf(q0, awl.y, q1 * awh.y)) + bb1;
            float m2 = wred_sum(fmaf(q0, awl.z, q1 * awh.z)) + bb2;
            float m3 = wred_sum(fmaf(q0, awl.w, q1 * awh.w)) + bb3;
            const float mx = fmaxf(fmaxf(m0, m1), fmaxf(m2, m3));
            const float e0 = __expf(m0 - mx), e1 = __expf(m1 - mx);
            const float e2 = __expf(m2 - mx), e3 = __expf(m3 - mx);
            const float inv = 1.f / (e0 + e1 + e2 + e3);
            if (lane == 0)
                *(float4*)&attn_sm[l * 4] =
                    make_float4(e0 * inv, e1 * inv, e2 * inv, e3 * inv);
        }
    }
    __syncthreads();

    // ---- matrix_z / attention_embs -> cat[0:128]; user_emb -> cat[128:256] ----
    if (tid < 128) {
        const int d = tid;
        float z0 = 0.f, z1 = 0.f, z2 = 0.f, z3 = 0.f;
        for (int l = 0; l < L_; ++l) {
            const float xv = x[l][d];
            const float4 at = *(const float4*)&attn_sm[l * 4];
            z0 = fmaf(xv, at.x, z0);
            z1 = fmaf(xv, at.y, z1);
            z2 = fmaf(xv, at.z, z2);
            z3 = fmaf(xv, at.w, z3);
        }
        cat[d] = 0.25f * (tanhf(z0) + tanhf(z1) + tanhf(z2) + tanhf(z3));
    } else {
        const int d = tid - 128;
        const int uid = uids[b];
        cat[tid] = user_emb[(size_t)uid * D_ + d];
    }
    __syncthreads();

    // ---- fusion = cat @ user_com; v = fusion + s ----
    {
        const int g = tid & 127, hf = tid >> 7;
        float acc = 0.f;
        const float* ucb = user_com + hf * 128 * 128 + g;
        const float* cc = &cat[hf * 128];
#pragma unroll 4
        for (int k = 0; k < 128; ++k) acc = fmaf(cc[k], ucb[(size_t)k * 128], acc);
        if (hf) fpart[g] = acc;
        __syncthreads();
        if (!hf) vvec[g] = acc + fpart[g] + sval;  // sval: register copy of s[g]
    }
    __syncthreads();

    // ---- out[b,t] = w2[t]·v + b2[t] ----
    {
        const float vl = vvec[lane], vh = vvec[lane + 64];
        const int* itpb = itp + b * T_;
        for (int t = w; t < T_; t += 4) {
            const int item = itpb[t];
            const float* w2r = W2t + (size_t)item * D_;
            float r = fmaf(w2r[lane], vl, w2r[lane + 64] * vh);
            r = wred_sum(r);
            if (lane == 0) out[b * T_ + t] = r + b2t[item];
        }
    }
}

extern "C" void kernel_launch(void* const* d_in, const int* in_sizes, int n_in,
                              void* d_out, int out_size, void* d_ws, size_t ws_size,
                              hipStream_t stream) {
    const int* iseq = (const int*)d_in[0];
    const int* uids = (const int*)d_in[1];
    const int* itp = (const int*)d_in[2];
    const int* A = (const int*)d_in[3];
    const float* item_emb = (const float*)d_in[4];
    const float* user_emb = (const float*)d_in[5];
    const float* W2t = (const float*)d_in[6];
    const float* b2t = (const float*)d_in[7];
    const float* W_att = (const float*)d_in[8];
    const float* a_att = (const float*)d_in[9];
    const float* W_out = (const float*)d_in[10];
    const float* a_out = (const float*)d_in[11];
    const float* att1_W = (const float*)d_in[12];
    const float* att1_b = (const float*)d_in[13];
    const float* att2_W = (const float*)d_in[14];
    const float* att2_b = (const float*)d_in[15];
    const float* user_com = (const float*)d_in[16];
    float* out = (float*)d_out;

    const int B = in_sizes[1];  // user_ids is (B,)
    magnn_fused<<<dim3(B), dim3(256), 0, stream>>>(
        iseq, uids, itp, A, item_emb, user_emb, W2t, b2t, W_att, a_att, W_out,
        a_out, att1_W, att1_b, att2_W, att2_b, user_com, out);
}